// Round 2
// baseline (307.243 us; speedup 1.0000x reference)
//
#include <hip/hip_runtime.h>
#include <stdint.h>

#define DEVI __device__ __forceinline__

typedef short bf16x8 __attribute__((ext_vector_type(8)));
typedef float f32x4  __attribute__((ext_vector_type(4)));

DEVI short f2bf(float f){
  union { float f; uint32_t u; } un; un.f = f;
  uint32_t u = un.u;
  u += 0x7fffu + ((u >> 16) & 1u);   // RNE
  return (short)(u >> 16);
}

DEVI f32x4 mfma16(bf16x8 a, bf16x8 b, f32x4 c){
  return __builtin_amdgcn_mfma_f32_16x16x32_bf16(a, b, c, 0, 0, 0);
}

// ---------- prep: transpose fp32 [R][C] -> bf16 [C][R] ----------
__global__ void transpose_bf(const float* __restrict__ W, short* __restrict__ WT,
                             int R, int C){
  __shared__ float tile[32][33];
  int ctiles = C >> 5;
  int bi = blockIdx.x / ctiles, bj = blockIdx.x % ctiles;
  int tx = threadIdx.x & 31, ty = threadIdx.x >> 5;
  #pragma unroll
  for (int r = 0; r < 4; ++r){
    int i = bi*32 + ty + r*8;
    tile[ty + r*8][tx] = W[(size_t)i*C + bj*32 + tx];
  }
  __syncthreads();
  #pragma unroll
  for (int r = 0; r < 4; ++r){
    int j = bj*32 + ty + r*8;
    WT[(size_t)j*R + bi*32 + tx] = f2bf(tile[tx][ty + r*8]);
  }
}

// ---------- prep: hvb = bf16(h_v * V), ub = bf16(u) ----------
__global__ void prep_hv(const float* __restrict__ hv, const float* __restrict__ V,
                        const float* __restrict__ u, short* __restrict__ hvb,
                        short* __restrict__ ub){
  int idx = blockIdx.x*256 + threadIdx.x;
  if (idx < 512*256){
    int r = idx >> 8;
    hvb[idx] = f2bf(hv[idx] * V[r]);
  } else if (idx < 512*256 + 1024){
    int i2 = idx - 512*256;
    ub[i2] = f2bf(u[i2]);
  }
}

// ---------- prep: s[k,n,j] = hv[k,n]*W1[0:256] + u[k]*W1[512:768] + b1
//                  t[k,m,j] = hv[k,m]*W1[256:512] ----------
__global__ __launch_bounds__(256) void prep_st(
    const short* __restrict__ hvb, const short* __restrict__ ub,
    const short* __restrict__ w1t, const float* __restrict__ b1,
    float* __restrict__ sbuf, float* __restrict__ tbuf)
{
  const int bid = blockIdx.x;
  const int st = bid >> 7;           // 0 = s, 1 = t
  const int rt8 = (bid >> 4) & 7;    // 8 row tiles of 64 over 512 rows
  const int ctile = bid & 15;        // 16 col tiles of 64 over 1024 cols
  const int r0 = rt8 << 6, j0 = ctile << 6;
  const int tid = threadIdx.x;
  const int w = tid >> 6, l = tid & 63;
  const int l15 = l & 15, l4 = l >> 4;
  __shared__ short A[64*256];
  for (int q = 0; q < 8; ++q){
    int id = tid + (q << 8);
    int row = id >> 5, c8 = id & 31;
    bf16x8 v = *(const bf16x8*)(hvb + (size_t)(r0 + row)*256 + c8*8);
    *(bf16x8*)((char*)A + row*512 + ((c8*16) ^ ((row & 7) << 4))) = v;
  }
  __syncthreads();
  const int wr = w >> 1, wc = w & 1;
  const int rowbase = wr << 5, colbase = wc << 5;
  const int swzA = (l15 & 7) << 4;
  f32x4 acc[2][2];
  acc[0][0]=0; acc[0][1]=0; acc[1][0]=0; acc[1][1]=0;
  const int ioff = st ? 256 : 0;
  const short* w1p = w1t + (size_t)(j0 + colbase + l15)*1024 + ioff + l4*8;
  const char* ap0 = (const char*)A + (rowbase + l15)*512;
  const char* ap1 = ap0 + 16*512;
  #pragma unroll
  for (int kk = 0; kk < 8; ++kk){
    int ib = kk*64 + l4*16;
    bf16x8 a0 = *(const bf16x8*)(ap0 + (ib ^ swzA));
    bf16x8 a1 = *(const bf16x8*)(ap1 + (ib ^ swzA));
    bf16x8 b0 = *(const bf16x8*)(w1p + kk*32);
    bf16x8 b1v = *(const bf16x8*)(w1p + 16*1024 + kk*32);
    acc[0][0] = mfma16(a0, b0, acc[0][0]);
    acc[1][0] = mfma16(a1, b0, acc[1][0]);
    acc[0][1] = mfma16(a0, b1v, acc[0][1]);
    acc[1][1] = mfma16(a1, b1v, acc[1][1]);
  }
  if (st == 0){
    const int kb = r0 >> 7;
    const short* up = ub + kb*256 + l4*8;
    const short* w1pu = w1t + (size_t)(j0 + colbase + l15)*1024 + 512 + l4*8;
    #pragma unroll
    for (int kk = 0; kk < 8; ++kk){
      bf16x8 au = *(const bf16x8*)(up + kk*32);
      bf16x8 b0 = *(const bf16x8*)(w1pu + kk*32);
      bf16x8 b1v = *(const bf16x8*)(w1pu + 16*1024 + kk*32);
      acc[0][0] = mfma16(au, b0, acc[0][0]);
      acc[1][0] = mfma16(au, b0, acc[1][0]);
      acc[0][1] = mfma16(au, b1v, acc[0][1]);
      acc[1][1] = mfma16(au, b1v, acc[1][1]);
    }
  }
  float* dst = st ? tbuf : sbuf;
  #pragma unroll
  for (int r = 0; r < 2; ++r){
    #pragma unroll
    for (int c = 0; c < 2; ++c){
      int jg = j0 + colbase + c*16 + l15;
      float badd = st ? 0.f : b1[jg];
      #pragma unroll
      for (int reg = 0; reg < 4; ++reg){
        int rowl = rowbase + r*16 + l4*4 + reg;
        dst[(size_t)(r0 + rowl)*1024 + jg] = acc[r][c][reg] + badd;
      }
    }
  }
}

// ---------- main fused kernel ----------
// block = (k, n, m-half): 64 rows (m), full 256 outputs
__global__ __launch_bounds__(256, 2) void fused_edge(
    const float* __restrict__ he, const float* __restrict__ sbuf,
    const float* __restrict__ tbuf, const short* __restrict__ w1t,
    const short* __restrict__ w2t, const float* __restrict__ b2,
    const int* __restrict__ Em, float* __restrict__ out)
{
  const int b = blockIdx.x;
  const int k = b >> 8;
  const int n = (b >> 1) & 127;
  const int m0 = (b & 1) << 6;
  const int tid = threadIdx.x;
  const int w = tid >> 6, l = tid & 63;
  const int l15 = l & 15, l4 = l >> 4;

  __shared__ short heb[64*256];      // bf16 h_e tile, XOR-swizzled
  __shared__ short eluv[2][64*64];   // double-buffered ELU(z1) chunk

  const int grow0 = ((k << 7) + n)*128 + m0;
  const float* hesrc = he + (size_t)grow0 * 256;

  // stage h_e[k,n,m0:m0+64,:] -> bf16 LDS (swizzled): 2048 bf16x8 chunks, 8/thread
  #pragma unroll
  for (int q = 0; q < 8; ++q){
    int id = tid + (q << 8);
    int row = id >> 5, c8 = id & 31;
    const float4* p = (const float4*)(hesrc + row*256 + c8*8);
    float4 a4 = p[0], b4 = p[1];
    union { bf16x8 v; short s[8]; } pk;
    pk.s[0]=f2bf(a4.x); pk.s[1]=f2bf(a4.y); pk.s[2]=f2bf(a4.z); pk.s[3]=f2bf(a4.w);
    pk.s[4]=f2bf(b4.x); pk.s[5]=f2bf(b4.y); pk.s[6]=f2bf(b4.z); pk.s[7]=f2bf(b4.w);
    *(bf16x8*)((char*)heb + row*512 + ((c8*16) ^ ((row & 7) << 4))) = pk.v;
  }
  __syncthreads();

  const int wr = w >> 1, wc = w & 1;
  const int rowbase = wr << 5, colbase = wc << 5;
  const int swzA = (l15 & 7) << 4;

  f32x4 acc2[4][4];
  #pragma unroll
  for (int i = 0; i < 4; ++i)
    #pragma unroll
    for (int j = 0; j < 4; ++j) acc2[i][j] = 0;

  const float* srow = sbuf + (size_t)((k << 7) + n)*1024;
  const float* trow = tbuf + (size_t)((k << 7) + m0)*1024;

  for (int jc = 0; jc < 16; ++jc){
    // ---- GEMM1: z1[64 x 64] = heb @ W1[768:1024, jc*64 : jc*64+64] ----
    f32x4 acc1[2][2];
    acc1[0][0]=0; acc1[0][1]=0; acc1[1][0]=0; acc1[1][1]=0;
    const short* w1p = w1t + (size_t)(jc*64 + colbase + l15)*1024 + 768 + l4*8;
    const char* hp0 = (const char*)heb + (rowbase + l15)*512;
    const char* hp1 = hp0 + 16*512;
    #pragma unroll
    for (int kk = 0; kk < 8; ++kk){
      int ib = kk*64 + l4*16;
      bf16x8 a0 = *(const bf16x8*)(hp0 + (ib ^ swzA));
      bf16x8 a1 = *(const bf16x8*)(hp1 + (ib ^ swzA));
      bf16x8 b0 = *(const bf16x8*)(w1p + kk*32);
      bf16x8 b1 = *(const bf16x8*)(w1p + 16*1024 + kk*32);
      acc1[0][0] = mfma16(a0, b0, acc1[0][0]);
      acc1[1][0] = mfma16(a1, b0, acc1[1][0]);
      acc1[0][1] = mfma16(a0, b1, acc1[0][1]);
      acc1[1][1] = mfma16(a1, b1, acc1[1][1]);
    }

    // ---- add s + t, ELU, write bf16 chunk to LDS ----
    short* ebuf = eluv[jc & 1];
    float s0 = srow[jc*64 + colbase + l15];
    float s1 = srow[jc*64 + colbase + 16 + l15];
    #pragma unroll
    for (int r = 0; r < 2; ++r){
      #pragma unroll
      for (int reg = 0; reg < 4; ++reg){
        int ml = rowbase + r*16 + l4*4 + reg;
        const float* tp = trow + (size_t)ml*1024 + jc*64 + colbase + l15;
        float v0 = acc1[r][0][reg] + s0 + tp[0];
        float v1 = acc1[r][1][reg] + s1 + tp[16];
        v0 = v0 > 0.f ? v0 : (__expf(v0) - 1.f);
        v1 = v1 > 0.f ? v1 : (__expf(v1) - 1.f);
        int rowoff = ml*128;
        int sw = (ml & 7) << 4;
        int j0b = (colbase + l15)*2;
        int j1b = (colbase + 16 + l15)*2;
        *(short*)((char*)ebuf + rowoff + (j0b ^ sw)) = f2bf(v0);
        *(short*)((char*)ebuf + rowoff + (j1b ^ sw)) = f2bf(v1);
      }
    }
    __syncthreads();

    // ---- GEMM2: acc2 += ELU-chunk @ W2[jc*64 : jc*64+64, :], wave owns 64 out cols ----
    const short* eb = eluv[jc & 1];
    const short* w2p = w2t + (size_t)(w*64 + l15)*1024 + jc*64 + l4*8;
    #pragma unroll
    for (int kk2 = 0; kk2 < 2; ++kk2){
      int jb = kk2*64 + l4*16;
      bf16x8 a[4];
      #pragma unroll
      for (int rt = 0; rt < 4; ++rt){
        int row = rt*16 + l15;
        a[rt] = *(const bf16x8*)((const char*)eb + row*128 + (jb ^ swzA));
      }
      #pragma unroll
      for (int q = 0; q < 4; ++q){
        bf16x8 bb = *(const bf16x8*)(w2p + (size_t)q*16*1024 + kk2*32);
        #pragma unroll
        for (int rt = 0; rt < 4; ++rt)
          acc2[rt][q] = mfma16(a[rt], bb, acc2[rt][q]);
      }
    }
  }

  // ---- epilogue: + b2, E-mask, + h_e (fp32 exact), store ----
  float bias[4];
  #pragma unroll
  for (int q = 0; q < 4; ++q) bias[q] = b2[w*64 + q*16 + l15];
  #pragma unroll
  for (int rt = 0; rt < 4; ++rt){
    #pragma unroll
    for (int reg = 0; reg < 4; ++reg){
      int m = rt*16 + l4*4 + reg;
      size_t grow = (size_t)(grow0 + m);
      int e = Em[grow*2 + 1];
      const float* hep = he + grow*256 + w*64 + l15;
      float* op = out + grow*256 + w*64 + l15;
      #pragma unroll
      for (int q = 0; q < 4; ++q){
        float v = (e == 1) ? (acc2[rt][q][reg] + bias[q]) : 0.f;
        op[q*16] = v + hep[q*16];
      }
    }
  }
}

extern "C" void kernel_launch(void* const* d_in, const int* in_sizes, int n_in,
                              void* d_out, int out_size, void* d_ws, size_t ws_size,
                              hipStream_t stream)
{
  const float* u   = (const float*)d_in[0];
  const float* h_v = (const float*)d_in[1];
  const float* h_e = (const float*)d_in[2];
  const float* V   = (const float*)d_in[3];
  const int*   E   = (const int*)d_in[4];
  const float* W1  = (const float*)d_in[5];
  const float* b1  = (const float*)d_in[6];
  const float* W2  = (const float*)d_in[7];
  const float* b2  = (const float*)d_in[8];
  float* out = (float*)d_out;

  char* ws = (char*)d_ws;
  short* w1t  = (short*)(ws);                               // 2 MB  bf16 W1^T [1024][1024]
  short* w2t  = (short*)(ws + (2u<<20));                    // 512KB bf16 W2^T [256][1024]
  short* hvb  = (short*)(ws + (2u<<20) + (512u<<10));       // 256KB bf16 masked h_v [512][256]
  short* ub   = (short*)(ws + (2u<<20) + (768u<<10));       // 2KB   bf16 u [4][256]
  float* sbuf = (float*)(ws + (3u<<20));                    // 2 MB  fp32 s [512][1024]
  float* tbuf = (float*)(ws + (5u<<20));                    // 2 MB  fp32 t [512][1024]

  transpose_bf<<<1024, 256, 0, stream>>>(W1, w1t, 1024, 1024);
  transpose_bf<<<256,  256, 0, stream>>>(W2, w2t, 1024, 256);
  prep_hv<<<516, 256, 0, stream>>>(h_v, V, u, hvb, ub);
  prep_st<<<256, 256, 0, stream>>>(hvb, ub, w1t, b1, sbuf, tbuf);
  fused_edge<<<1024, 256, 0, stream>>>(h_e, sbuf, tbuf, w1t, w2t, b2, E, out);
}

// Round 4
// 260.537 us; speedup vs baseline: 1.1793x; 1.1793x over previous
//
#include <hip/hip_runtime.h>
#include <stdint.h>

#define DEVI __device__ __forceinline__

typedef short bf16x8 __attribute__((ext_vector_type(8)));
typedef float f32x4  __attribute__((ext_vector_type(4)));

DEVI short f2bf(float f){
  union { float f; uint32_t u; } un; un.f = f;
  uint32_t u = un.u;
  u += 0x7fffu + ((u >> 16) & 1u);   // RNE
  return (short)(u >> 16);
}
DEVI float bf2f(uint32_t us){
  union { uint32_t u; float f; } x; x.u = us << 16; return x.f;
}

DEVI f32x4 mfma16(bf16x8 a, bf16x8 b, f32x4 c){
  return __builtin_amdgcn_mfma_f32_16x16x32_bf16(a, b, c, 0, 0, 0);
}

// ---------- prep: transpose fp32 [R][C] -> bf16 [C][R] ----------
__global__ void transpose_bf(const float* __restrict__ W, short* __restrict__ WT,
                             int R, int C){
  __shared__ float tile[32][33];
  int ctiles = C >> 5;
  int bi = blockIdx.x / ctiles, bj = blockIdx.x % ctiles;
  int tx = threadIdx.x & 31, ty = threadIdx.x >> 5;
  #pragma unroll
  for (int r = 0; r < 4; ++r){
    int i = bi*32 + ty + r*8;
    tile[ty + r*8][tx] = W[(size_t)i*C + bj*32 + tx];
  }
  __syncthreads();
  #pragma unroll
  for (int r = 0; r < 4; ++r){
    int j = bj*32 + ty + r*8;
    WT[(size_t)j*R + bi*32 + tx] = f2bf(tile[tx][ty + r*8]);
  }
}

// ---------- prep: hvb = bf16(h_v * V), ub = bf16(u) ----------
__global__ void prep_hv(const float* __restrict__ hv, const float* __restrict__ V,
                        const float* __restrict__ u, short* __restrict__ hvb,
                        short* __restrict__ ub){
  int idx = blockIdx.x*256 + threadIdx.x;
  if (idx < 512*256){
    int r = idx >> 8;
    hvb[idx] = f2bf(hv[idx] * V[r]);
  } else if (idx < 512*256 + 1024){
    int i2 = idx - 512*256;
    ub[i2] = f2bf(u[i2]);
  }
}

// ---------- prep: s[k,n,j] = hv[k,n]*W1[0:256] + u[k]*W1[512:768] + b1  (bf16 out)
//                  t[k,m,j] = hv[k,m]*W1[256:512]                        (bf16 out)
__global__ __launch_bounds__(256) void prep_st(
    const short* __restrict__ hvb, const short* __restrict__ ub,
    const short* __restrict__ w1t, const float* __restrict__ b1,
    short* __restrict__ sbuf, short* __restrict__ tbuf)
{
  const int bid = blockIdx.x;
  const int st = bid >> 7;           // 0 = s, 1 = t
  const int rt8 = (bid >> 4) & 7;    // 8 row tiles of 64 over 512 rows
  const int ctile = bid & 15;        // 16 col tiles of 64 over 1024 cols
  const int r0 = rt8 << 6, j0 = ctile << 6;
  const int tid = threadIdx.x;
  const int w = tid >> 6, l = tid & 63;
  const int l15 = l & 15, l4 = l >> 4;
  __shared__ short A[64*256];
  for (int q = 0; q < 8; ++q){
    int id = tid + (q << 8);
    int row = id >> 5, c8 = id & 31;
    bf16x8 v = *(const bf16x8*)(hvb + (size_t)(r0 + row)*256 + c8*8);
    *(bf16x8*)((char*)A + row*512 + ((c8*16) ^ ((row & 7) << 4))) = v;
  }
  __syncthreads();
  const int wr = w >> 1, wc = w & 1;
  const int rowbase = wr << 5, colbase = wc << 5;
  const int swzA = (l15 & 7) << 4;
  f32x4 acc[2][2];
  acc[0][0]=0; acc[0][1]=0; acc[1][0]=0; acc[1][1]=0;
  const int ioff = st ? 256 : 0;
  const short* w1p = w1t + (size_t)(j0 + colbase + l15)*1024 + ioff + l4*8;
  const char* ap0 = (const char*)A + (rowbase + l15)*512;
  const char* ap1 = ap0 + 16*512;
  #pragma unroll
  for (int kk = 0; kk < 8; ++kk){
    int ib = kk*64 + l4*16;
    bf16x8 a0 = *(const bf16x8*)(ap0 + (ib ^ swzA));
    bf16x8 a1 = *(const bf16x8*)(ap1 + (ib ^ swzA));
    bf16x8 b0 = *(const bf16x8*)(w1p + kk*32);
    bf16x8 b1v = *(const bf16x8*)(w1p + 16*1024 + kk*32);
    acc[0][0] = mfma16(a0, b0, acc[0][0]);
    acc[1][0] = mfma16(a1, b0, acc[1][0]);
    acc[0][1] = mfma16(a0, b1v, acc[0][1]);
    acc[1][1] = mfma16(a1, b1v, acc[1][1]);
  }
  if (st == 0){
    const int kb = r0 >> 7;
    const short* up = ub + kb*256 + l4*8;
    const short* w1pu = w1t + (size_t)(j0 + colbase + l15)*1024 + 512 + l4*8;
    #pragma unroll
    for (int kk = 0; kk < 8; ++kk){
      bf16x8 au = *(const bf16x8*)(up + kk*32);
      bf16x8 b0 = *(const bf16x8*)(w1pu + kk*32);
      bf16x8 b1v = *(const bf16x8*)(w1pu + 16*1024 + kk*32);
      acc[0][0] = mfma16(au, b0, acc[0][0]);
      acc[1][0] = mfma16(au, b0, acc[1][0]);
      acc[0][1] = mfma16(au, b1v, acc[0][1]);
      acc[1][1] = mfma16(au, b1v, acc[1][1]);
    }
  }
  short* dst = st ? tbuf : sbuf;
  #pragma unroll
  for (int r = 0; r < 2; ++r){
    #pragma unroll
    for (int c = 0; c < 2; ++c){
      int jg = j0 + colbase + c*16 + l15;
      float badd = st ? 0.f : b1[jg];
      #pragma unroll
      for (int reg = 0; reg < 4; ++reg){
        int rowl = rowbase + r*16 + l4*4 + reg;
        dst[(size_t)(r0 + rowl)*1024 + jg] = f2bf(acc[r][c][reg] + badd);
      }
    }
  }
}

// ---------- main fused kernel ----------
// block = (k, n, m-half): 64 rows (m), full 256 outputs. 4 waves.
// GEMM1: wave w owns hidden cols [jc*64 + w*16, +16) over all 64 rows  (no B dup)
// GEMM2: wave w owns out cols [w*64, +64) over all 64 rows
__global__ __launch_bounds__(256, 3) void fused_edge(
    const float* __restrict__ he, const unsigned short* __restrict__ sb,
    const unsigned short* __restrict__ tb, const short* __restrict__ w1t,
    const short* __restrict__ w2t, const float* __restrict__ b2,
    const int* __restrict__ Em, float* __restrict__ out)
{
  const int b = blockIdx.x;
  const int k = b >> 8;
  const int n = (b >> 1) & 127;
  const int m0 = (b & 1) << 6;
  const int tid = threadIdx.x;
  const int w = tid >> 6, l = tid & 63;
  const int l15 = l & 15, l4 = l >> 4;

  __shared__ short heb[64*256];      // bf16 h_e tile, XOR-swizzled  (32 KB)
  __shared__ short eluv[2][64*64];   // double-buffered ELU chunk    (16 KB)
  __shared__ int   emask[64];

  const int grow0 = ((k << 7) + n)*128 + m0;
  const float* hesrc = he + (size_t)grow0 * 256;

  // stage h_e[k,n,m0:m0+64,:] -> bf16 LDS (swizzled): 2048 bf16x8 chunks, 8/thread
  #pragma unroll
  for (int q = 0; q < 8; ++q){
    int id = tid + (q << 8);
    int row = id >> 5, c8 = id & 31;
    const float4* p = (const float4*)(hesrc + row*256 + c8*8);
    float4 a4 = p[0], b4 = p[1];
    union { bf16x8 v; short s[8]; } pk;
    pk.s[0]=f2bf(a4.x); pk.s[1]=f2bf(a4.y); pk.s[2]=f2bf(a4.z); pk.s[3]=f2bf(a4.w);
    pk.s[4]=f2bf(b4.x); pk.s[5]=f2bf(b4.y); pk.s[6]=f2bf(b4.z); pk.s[7]=f2bf(b4.w);
    *(bf16x8*)((char*)heb + row*512 + ((c8*16) ^ ((row & 7) << 4))) = pk.v;
  }
  if (tid < 64) emask[tid] = Em[(size_t)(grow0 + tid)*2 + 1];
  __syncthreads();

  f32x4 acc2[4][4];
  #pragma unroll
  for (int i = 0; i < 4; ++i)
    #pragma unroll
    for (int j = 0; j < 4; ++j) acc2[i][j] = 0;

  const unsigned short* srow  = sb + (size_t)((k << 7) + n)*1024;
  const unsigned short* trowb = tb + (size_t)((k << 7) + m0)*1024;
  const char* hb = (const char*)heb;
  const int swz = (l15 & 7) << 4;

  for (int jc = 0; jc < 16; ++jc){
    const int jcol = jc*64 + w*16 + l15;

    // ---- issue t-loads for this jc (consumed in ELU; hidden under GEMM1) ----
    uint32_t traw[16];
    #pragma unroll
    for (int rt = 0; rt < 4; ++rt)
      #pragma unroll
      for (int reg = 0; reg < 4; ++reg)
        traw[rt*4+reg] = trowb[(size_t)(rt*16 + l4*4 + reg)*1024 + jcol];

    // ---- GEMM1: z1[64 x 16(w)] = heb @ W1[768:1024, jcol] ----
    const short* w1p = w1t + (size_t)jcol*1024 + 768 + l4*8;
    bf16x8 bw1[8];
    #pragma unroll
    for (int kk = 0; kk < 8; ++kk) bw1[kk] = *(const bf16x8*)(w1p + kk*32);

    f32x4 acc1[4];
    acc1[0]=0; acc1[1]=0; acc1[2]=0; acc1[3]=0;
    #pragma unroll
    for (int kk = 0; kk < 8; ++kk){
      int ib = kk*64 + l4*16;
      #pragma unroll
      for (int rt = 0; rt < 4; ++rt){
        int row = rt*16 + l15;
        bf16x8 a = *(const bf16x8*)(hb + row*512 + (ib ^ swz));
        acc1[rt] = mfma16(a, bw1[kk], acc1[rt]);
      }
    }

    // ---- issue w2 fragment loads (consumed after barrier; hidden under ELU) ----
    const short* w2p = w2t + (size_t)(w*64 + l15)*1024 + jc*64 + l4*8;
    bf16x8 bw2[4][2];
    #pragma unroll
    for (int q = 0; q < 4; ++q)
      #pragma unroll
      for (int kk2 = 0; kk2 < 2; ++kk2)
        bw2[q][kk2] = *(const bf16x8*)(w2p + (size_t)q*16*1024 + kk2*32);

    // ---- ELU: z1 + s + t, write bf16 to LDS (swizzled) ----
    char* eb = (char*)eluv[jc & 1];
    float sv = bf2f(srow[jcol]);
    #pragma unroll
    for (int rt = 0; rt < 4; ++rt){
      #pragma unroll
      for (int reg = 0; reg < 4; ++reg){
        int row = rt*16 + l4*4 + reg;
        float v = acc1[rt][reg] + sv + bf2f(traw[rt*4+reg]);
        v = v > 0.f ? v : (__expf(v) - 1.f);
        *(short*)(eb + row*128 + ((((w*16 + l15)*2)) ^ ((row & 7) << 4))) = f2bf(v);
      }
    }
    __syncthreads();

    // ---- GEMM2: acc2 += ELU-chunk @ W2[jc*64:+64, w*64:+64] ----
    #pragma unroll
    for (int kk2 = 0; kk2 < 2; ++kk2){
      int jb = kk2*64 + l4*16;
      #pragma unroll
      for (int rt = 0; rt < 4; ++rt){
        int row = rt*16 + l15;
        bf16x8 a2 = *(const bf16x8*)(eb + row*128 + (jb ^ swz));
        #pragma unroll
        for (int q = 0; q < 4; ++q)
          acc2[rt][q] = mfma16(a2, bw2[q][kk2], acc2[rt][q]);
      }
    }
  }

  // ---- epilogue: + b2, E-mask, + h_e (fp32 exact), store ----
  float bias[4];
  #pragma unroll
  for (int q = 0; q < 4; ++q) bias[q] = b2[w*64 + q*16 + l15];
  #pragma unroll
  for (int rt = 0; rt < 4; ++rt){
    #pragma unroll
    for (int reg = 0; reg < 4; ++reg){
      int row = rt*16 + l4*4 + reg;
      int e = emask[row];
      size_t grow = (size_t)(grow0 + row);
      const float* hep = he + grow*256 + w*64 + l15;
      float* op = out + grow*256 + w*64 + l15;
      #pragma unroll
      for (int q = 0; q < 4; ++q){
        float v = (e == 1) ? (acc2[rt][q][reg] + bias[q]) : 0.f;
        op[q*16] = v + hep[q*16];
      }
    }
  }
}

extern "C" void kernel_launch(void* const* d_in, const int* in_sizes, int n_in,
                              void* d_out, int out_size, void* d_ws, size_t ws_size,
                              hipStream_t stream)
{
  const float* u   = (const float*)d_in[0];
  const float* h_v = (const float*)d_in[1];
  const float* h_e = (const float*)d_in[2];
  const float* V   = (const float*)d_in[3];
  const int*   E   = (const int*)d_in[4];
  const float* W1  = (const float*)d_in[5];
  const float* b1  = (const float*)d_in[6];
  const float* W2  = (const float*)d_in[7];
  const float* b2  = (const float*)d_in[8];
  float* out = (float*)d_out;

  char* ws = (char*)d_ws;
  short* w1t  = (short*)(ws);                               // 2 MB   bf16 W1^T [1024][1024]
  short* w2t  = (short*)(ws + (2u<<20));                    // 512KB  bf16 W2^T [256][1024]
  short* hvb  = (short*)(ws + (2u<<20) + (512u<<10));       // 256KB  bf16 masked h_v
  short* ub   = (short*)(ws + (2u<<20) + (768u<<10));       // 2KB    bf16 u
  short* sbuf = (short*)(ws + (3u<<20));                    // 1 MB   bf16 s [512][1024]
  short* tbuf = (short*)(ws + (4u<<20));                    // 1 MB   bf16 t [512][1024]

  transpose_bf<<<1024, 256, 0, stream>>>(W1, w1t, 1024, 1024);
  transpose_bf<<<256,  256, 0, stream>>>(W2, w2t, 1024, 256);
  prep_hv<<<516, 256, 0, stream>>>(h_v, V, u, hvb, ub);
  prep_st<<<256, 256, 0, stream>>>(hvb, ub, w1t, b1, sbuf, tbuf);
  fused_edge<<<1024, 256, 0, stream>>>(h_e,
                                       (const unsigned short*)sbuf,
                                       (const unsigned short*)tbuf,
                                       w1t, w2t, b2, E, out);
}

// Round 5
// 201.816 us; speedup vs baseline: 1.5224x; 1.2910x over previous
//
#include <hip/hip_runtime.h>
#include <stdint.h>

#define DEVI __device__ __forceinline__

typedef short bf16x8 __attribute__((ext_vector_type(8)));
typedef float f32x4  __attribute__((ext_vector_type(4)));

DEVI short f2bf(float f){
  union { float f; uint32_t u; } un; un.f = f;
  uint32_t u = un.u;
  u += 0x7fffu + ((u >> 16) & 1u);   // RNE
  return (short)(u >> 16);
}
DEVI float bf2f(uint32_t us){
  union { uint32_t u; float f; } x; x.u = us << 16; return x.f;
}

DEVI f32x4 mfma16(bf16x8 a, bf16x8 b, f32x4 c){
  return __builtin_amdgcn_mfma_f32_16x16x32_bf16(a, b, c, 0, 0, 0);
}

// ---------- prep: transpose fp32 [R][C] -> bf16 [C][R] ----------
__global__ void transpose_bf(const float* __restrict__ W, short* __restrict__ WT,
                             int R, int C){
  __shared__ float tile[32][33];
  int ctiles = C >> 5;
  int bi = blockIdx.x / ctiles, bj = blockIdx.x % ctiles;
  int tx = threadIdx.x & 31, ty = threadIdx.x >> 5;
  #pragma unroll
  for (int r = 0; r < 4; ++r){
    int i = bi*32 + ty + r*8;
    tile[ty + r*8][tx] = W[(size_t)i*C + bj*32 + tx];
  }
  __syncthreads();
  #pragma unroll
  for (int r = 0; r < 4; ++r){
    int j = bj*32 + ty + r*8;
    WT[(size_t)j*R + bi*32 + tx] = f2bf(tile[tx][ty + r*8]);
  }
}

// ---------- prep: hvb = bf16(h_v * V), ub = bf16(u) ----------
__global__ void prep_hv(const float* __restrict__ hv, const float* __restrict__ V,
                        const float* __restrict__ u, short* __restrict__ hvb,
                        short* __restrict__ ub){
  int idx = blockIdx.x*256 + threadIdx.x;
  if (idx < 512*256){
    int r = idx >> 8;
    hvb[idx] = f2bf(hv[idx] * V[r]);
  } else if (idx < 512*256 + 1024){
    int i2 = idx - 512*256;
    ub[i2] = f2bf(u[i2]);
  }
}

// ---------- prep: s[(k,n)][j] = hv*W1[0:256] + u*W1[512:768] + b1   (bf16, row-major)
//                  tT[j][(k,m)] = hv*W1[256:512]                     (bf16, TRANSPOSED)
__global__ __launch_bounds__(256) void prep_st(
    const short* __restrict__ hvb, const short* __restrict__ ub,
    const short* __restrict__ w1t, const float* __restrict__ b1,
    short* __restrict__ sbuf, short* __restrict__ tbuf)
{
  const int bid = blockIdx.x;
  const int st = bid >> 7;           // 0 = s, 1 = t
  const int rt8 = (bid >> 4) & 7;    // 8 row tiles of 64 over 512 rows
  const int ctile = bid & 15;        // 16 col tiles of 64 over 1024 cols
  const int r0 = rt8 << 6, j0 = ctile << 6;
  const int tid = threadIdx.x;
  const int w = tid >> 6, l = tid & 63;
  const int l15 = l & 15, l4 = l >> 4;
  __shared__ short A[64*256];
  for (int q = 0; q < 8; ++q){
    int id = tid + (q << 8);
    int row = id >> 5, c8 = id & 31;
    bf16x8 v = *(const bf16x8*)(hvb + (size_t)(r0 + row)*256 + c8*8);
    *(bf16x8*)((char*)A + row*512 + ((c8*16) ^ ((row & 7) << 4))) = v;
  }
  __syncthreads();
  const int wr = w >> 1, wc = w & 1;
  const int rowbase = wr << 5, colbase = wc << 5;
  const int swzA = (l15 & 7) << 4;
  f32x4 acc[2][2];
  acc[0][0]=0; acc[0][1]=0; acc[1][0]=0; acc[1][1]=0;
  const int ioff = st ? 256 : 0;
  const short* w1p = w1t + (size_t)(j0 + colbase + l15)*1024 + ioff + l4*8;
  const char* ap0 = (const char*)A + (rowbase + l15)*512;
  const char* ap1 = ap0 + 16*512;
  #pragma unroll
  for (int kk = 0; kk < 8; ++kk){
    int ib = kk*64 + l4*16;
    bf16x8 a0 = *(const bf16x8*)(ap0 + (ib ^ swzA));
    bf16x8 a1 = *(const bf16x8*)(ap1 + (ib ^ swzA));
    bf16x8 b0 = *(const bf16x8*)(w1p + kk*32);
    bf16x8 b1v = *(const bf16x8*)(w1p + 16*1024 + kk*32);
    acc[0][0] = mfma16(a0, b0, acc[0][0]);
    acc[1][0] = mfma16(a1, b0, acc[1][0]);
    acc[0][1] = mfma16(a0, b1v, acc[0][1]);
    acc[1][1] = mfma16(a1, b1v, acc[1][1]);
  }
  if (st == 0){
    const int kb = r0 >> 7;
    const short* up = ub + kb*256 + l4*8;
    const short* w1pu = w1t + (size_t)(j0 + colbase + l15)*1024 + 512 + l4*8;
    #pragma unroll
    for (int kk = 0; kk < 8; ++kk){
      bf16x8 au = *(const bf16x8*)(up + kk*32);
      bf16x8 b0 = *(const bf16x8*)(w1pu + kk*32);
      bf16x8 b1v = *(const bf16x8*)(w1pu + 16*1024 + kk*32);
      acc[0][0] = mfma16(au, b0, acc[0][0]);
      acc[1][0] = mfma16(au, b0, acc[1][0]);
      acc[0][1] = mfma16(au, b1v, acc[0][1]);
      acc[1][1] = mfma16(au, b1v, acc[1][1]);
    }
  }
  #pragma unroll
  for (int r = 0; r < 2; ++r){
    #pragma unroll
    for (int c = 0; c < 2; ++c){
      int jg = j0 + colbase + c*16 + l15;
      float badd = st ? 0.f : b1[jg];
      #pragma unroll
      for (int reg = 0; reg < 4; ++reg){
        int rowl = rowbase + r*16 + l4*4 + reg;
        if (st == 0)
          sbuf[(size_t)(r0 + rowl)*1024 + jg] = f2bf(acc[r][c][reg] + badd);
        else
          tbuf[(size_t)jg*512 + (r0 + rowl)] = f2bf(acc[r][c][reg]);
      }
    }
  }
}

// ---------- main fused kernel ----------
// block = (k, n, m-half): 64 rows (m), full 256 outputs. 4 waves.
// GEMM1: wave w owns hidden cols [jc*64 + w*16, +16) over all 64 rows
// GEMM2: wave w owns out cols [w*64, +64) over all 64 rows
// Pipeline: bw1 for jc+1 reloaded right after GEMM1 (regs dead);
//           t4/sv for jc+1 reloaded right after ELU; bw2 split around barrier.
__global__ __launch_bounds__(256, 3) void fused_edge(
    const float* __restrict__ he, const unsigned short* __restrict__ sb,
    const unsigned short* __restrict__ tbT, const short* __restrict__ w1t,
    const short* __restrict__ w2t, const float* __restrict__ b2,
    const int* __restrict__ Em, float* __restrict__ out)
{
  const int b = blockIdx.x;
  const int k = b >> 8;
  const int n = (b >> 1) & 127;
  const int m0 = (b & 1) << 6;
  const int tid = threadIdx.x;
  const int w = tid >> 6, l = tid & 63;
  const int l15 = l & 15, l4 = l >> 4;

  __shared__ short heb[64*256];      // bf16 h_e tile, XOR-swizzled  (32 KB)
  __shared__ short eluv[2][64*64];   // double-buffered ELU chunk    (16 KB) -> 48 KB total

  const int grow0 = ((k << 7) + n)*128 + m0;
  const float* hesrc = he + (size_t)grow0 * 256;

  // stage h_e[k,n,m0:m0+64,:] -> bf16 LDS (swizzled): 2048 bf16x8 chunks, 8/thread
  #pragma unroll
  for (int q = 0; q < 8; ++q){
    int id = tid + (q << 8);
    int row = id >> 5, c8 = id & 31;
    const float4* p = (const float4*)(hesrc + row*256 + c8*8);
    float4 a4 = p[0], b4 = p[1];
    union { bf16x8 v; short s[8]; } pk;
    pk.s[0]=f2bf(a4.x); pk.s[1]=f2bf(a4.y); pk.s[2]=f2bf(a4.z); pk.s[3]=f2bf(a4.w);
    pk.s[4]=f2bf(b4.x); pk.s[5]=f2bf(b4.y); pk.s[6]=f2bf(b4.z); pk.s[7]=f2bf(b4.w);
    *(bf16x8*)((char*)heb + row*512 + ((c8*16) ^ ((row & 7) << 4))) = pk.v;
  }
  __syncthreads();

  f32x4 acc2[4][4];
  #pragma unroll
  for (int i = 0; i < 4; ++i)
    #pragma unroll
    for (int j = 0; j < 4; ++j) acc2[i][j] = 0;

  const unsigned short* srow = sb  + (size_t)((k << 7) + n)*1024;
  const unsigned short* tcol = tbT + (size_t)((k << 7) + m0);   // tT[j][512] base at m0
  const char* hb = (const char*)heb;
  const int swz = (l15 & 7) << 4;

  union u4 { ushort4 v; unsigned short s[4]; };

  // ---- prologue: loads for jc = 0 ----
  bf16x8 bw1[8];
  {
    const short* w1p = w1t + (size_t)(w*16 + l15)*1024 + 768 + l4*8;
    #pragma unroll
    for (int kk = 0; kk < 8; ++kk) bw1[kk] = *(const bf16x8*)(w1p + kk*32);
  }
  u4 t4[4];
  #pragma unroll
  for (int rt = 0; rt < 4; ++rt)
    t4[rt].v = *(const ushort4*)(tcol + (size_t)(w*16 + l15)*512 + rt*16 + l4*4);
  float sv = bf2f(srow[w*16 + l15]);

  #pragma unroll
  for (int jc = 0; jc < 16; ++jc){
    const int jcol = jc*64 + w*16 + l15;

    // ---- GEMM1: z1[64 x 16(w)] = heb @ W1[768:1024, jcol] ----
    f32x4 acc1[4];
    acc1[0]=0; acc1[1]=0; acc1[2]=0; acc1[3]=0;
    #pragma unroll
    for (int kk = 0; kk < 8; ++kk){
      int ib = kk*64 + l4*16;
      #pragma unroll
      for (int rt = 0; rt < 4; ++rt){
        int row = rt*16 + l15;
        bf16x8 a = *(const bf16x8*)(hb + row*512 + (ib ^ swz));
        acc1[rt] = mfma16(a, bw1[kk], acc1[rt]);
      }
    }

    // ---- issue W2 first half (consumed after barrier; hidden under ELU+bar) ----
    const short* w2p = w2t + (size_t)(w*64 + l15)*1024 + jc*64 + l4*8;
    bf16x8 bw2a[4];
    #pragma unroll
    for (int q = 0; q < 4; ++q)
      bw2a[q] = *(const bf16x8*)(w2p + (size_t)q*16*1024);

    // ---- reload bw1 for jc+1 (regs dead after GEMM1; hidden under ELU+bar+GEMM2) ----
    if (jc < 15){
      const short* w1p = w1t + (size_t)(jcol + 64)*1024 + 768 + l4*8;
      #pragma unroll
      for (int kk = 0; kk < 8; ++kk) bw1[kk] = *(const bf16x8*)(w1p + kk*32);
    }

    // ---- ELU: z1 + s + t, write bf16 to LDS (swizzled) ----
    char* eb = (char*)eluv[jc & 1];
    #pragma unroll
    for (int rt = 0; rt < 4; ++rt){
      #pragma unroll
      for (int reg = 0; reg < 4; ++reg){
        int row = rt*16 + l4*4 + reg;
        float v = acc1[rt][reg] + sv + bf2f(t4[rt].s[reg]);
        v = v > 0.f ? v : (__expf(v) - 1.f);
        *(short*)(eb + row*128 + ((((w*16 + l15)*2)) ^ ((row & 7) << 4))) = f2bf(v);
      }
    }

    // ---- reload t4/sv for jc+1 (hidden under bar+GEMM2+GEMM1) ----
    if (jc < 15){
      #pragma unroll
      for (int rt = 0; rt < 4; ++rt)
        t4[rt].v = *(const ushort4*)(tcol + (size_t)(jcol + 64)*512 + rt*16 + l4*4);
      sv = bf2f(srow[jcol + 64]);
    }
    __syncthreads();

    // ---- GEMM2: acc2 += ELU-chunk @ W2[jc*64:+64, w*64:+64] ----
    // second half of W2 loads issued first, consumed after 16 MFMAs
    bf16x8 bw2b[4];
    #pragma unroll
    for (int q = 0; q < 4; ++q)
      bw2b[q] = *(const bf16x8*)(w2p + (size_t)q*16*1024 + 32);

    {
      int jb = l4*16;
      #pragma unroll
      for (int rt = 0; rt < 4; ++rt){
        int row = rt*16 + l15;
        bf16x8 a2 = *(const bf16x8*)(eb + row*128 + (jb ^ swz));
        #pragma unroll
        for (int q = 0; q < 4; ++q)
          acc2[rt][q] = mfma16(a2, bw2a[q], acc2[rt][q]);
      }
      jb = 64 + l4*16;
      #pragma unroll
      for (int rt = 0; rt < 4; ++rt){
        int row = rt*16 + l15;
        bf16x8 a2 = *(const bf16x8*)(eb + row*128 + (jb ^ swz));
        #pragma unroll
        for (int q = 0; q < 4; ++q)
          acc2[rt][q] = mfma16(a2, bw2b[q], acc2[rt][q]);
      }
    }
  }

  // ---- epilogue: + b2, E-mask, + h_e (fp32 exact), store ----
  float bias[4];
  #pragma unroll
  for (int q = 0; q < 4; ++q) bias[q] = b2[w*64 + q*16 + l15];
  #pragma unroll
  for (int rt = 0; rt < 4; ++rt){
    #pragma unroll
    for (int reg = 0; reg < 4; ++reg){
      int row = rt*16 + l4*4 + reg;
      size_t grow = (size_t)(grow0 + row);
      int2 ep = *(const int2*)(Em + grow*2);
      const float* hep = he + grow*256 + w*64 + l15;
      float* op = out + grow*256 + w*64 + l15;
      #pragma unroll
      for (int q = 0; q < 4; ++q){
        float v = (ep.y == 1) ? (acc2[rt][q][reg] + bias[q]) : 0.f;
        op[q*16] = v + hep[q*16];
      }
    }
  }
}

extern "C" void kernel_launch(void* const* d_in, const int* in_sizes, int n_in,
                              void* d_out, int out_size, void* d_ws, size_t ws_size,
                              hipStream_t stream)
{
  const float* u   = (const float*)d_in[0];
  const float* h_v = (const float*)d_in[1];
  const float* h_e = (const float*)d_in[2];
  const float* V   = (const float*)d_in[3];
  const int*   E   = (const int*)d_in[4];
  const float* W1  = (const float*)d_in[5];
  const float* b1  = (const float*)d_in[6];
  const float* W2  = (const float*)d_in[7];
  const float* b2  = (const float*)d_in[8];
  float* out = (float*)d_out;

  char* ws = (char*)d_ws;
  short* w1t  = (short*)(ws);                               // 2 MB   bf16 W1^T [1024][1024]
  short* w2t  = (short*)(ws + (2u<<20));                    // 512KB  bf16 W2^T [256][1024]
  short* hvb  = (short*)(ws + (2u<<20) + (512u<<10));       // 256KB  bf16 masked h_v
  short* ub   = (short*)(ws + (2u<<20) + (768u<<10));       // 2KB    bf16 u
  short* sbuf = (short*)(ws + (3u<<20));                    // 1 MB   bf16 s [512][1024]
  short* tbuf = (short*)(ws + (4u<<20));                    // 1 MB   bf16 tT [1024][512]

  transpose_bf<<<1024, 256, 0, stream>>>(W1, w1t, 1024, 1024);
  transpose_bf<<<256,  256, 0, stream>>>(W2, w2t, 1024, 256);
  prep_hv<<<516, 256, 0, stream>>>(h_v, V, u, hvb, ub);
  prep_st<<<256, 256, 0, stream>>>(hvb, ub, w1t, b1, sbuf, tbuf);
  fused_edge<<<1024, 256, 0, stream>>>(h_e,
                                       (const unsigned short*)sbuf,
                                       (const unsigned short*)tbuf,
                                       w1t, w2t, b2, E, out);
}